// Round 3
// baseline (11055.502 us; speedup 1.0000x reference)
//
#include <hip/hip_runtime.h>

// Persistent-kernel formulation.
// B=64, T=50, ROWS=COLS=64, RES=0.03, H_FULL=W_FULL=256
// flat = 14*14*32 = 6272 (stored TRANSPOSED: wsFlatT[k][b], k in [0,6272), b in [0,64))
// out: (64,51,6) float32
//
// Grid: 512 WGs x 256 threads, guaranteed co-resident:
//   LDS ~40KB (<=80KB for 2/CU), __launch_bounds__(256,2) caps VGPR for 8 waves/CU.
// Per step: phaseA(state+params, WG-local) -> conv -> GRID_BARRIER ->
//           dense0 -> GRID_BARRIER -> tail(h1+dense1+dense2 partials) -> GRID_BARRIER.

#define NWG 512

__device__ inline void grid_barrier(unsigned* __restrict__ cnt, unsigned* __restrict__ gen)
{
    __syncthreads();
    if (threadIdx.x == 0){
        __threadfence();   // agent-scope release: drains stores, writes back XCD L2
        unsigned g = __hip_atomic_load(gen, __ATOMIC_ACQUIRE, __HIP_MEMORY_SCOPE_AGENT);
        unsigned r = __hip_atomic_fetch_add(cnt, 1u, __ATOMIC_ACQ_REL, __HIP_MEMORY_SCOPE_AGENT);
        if (r == NWG - 1u){
            __hip_atomic_store(cnt, 0u, __ATOMIC_RELAXED, __HIP_MEMORY_SCOPE_AGENT);
            __hip_atomic_fetch_add(gen, 1u, __ATOMIC_RELEASE, __HIP_MEMORY_SCOPE_AGENT);
        } else {
            while (__hip_atomic_load(gen, __ATOMIC_RELAXED, __HIP_MEMORY_SCOPE_AGENT) == g){
                __builtin_amdgcn_s_sleep(2);
            }
        }
        __threadfence();   // agent-scope acquire: invalidates stale L1/L2
    }
    __syncthreads();
}

__global__ __launch_bounds__(256, 2)
void k_persist(const float* __restrict__ action, const float* __restrict__ state,
               const float* __restrict__ res, const float* __restrict__ env,
               const float* __restrict__ origin,
               const float* __restrict__ w1, const float* __restrict__ b1,
               const float* __restrict__ w2, const float* __restrict__ b2,
               const float* __restrict__ w0, const float* __restrict__ b0,
               const float* __restrict__ w1d, const float* __restrict__ b1d,
               const float* __restrict__ w2d, const float* __restrict__ b2d,
               float* __restrict__ out,
               float* __restrict__ wsFlatT, float* __restrict__ wsPart,
               float* __restrict__ wsDs, unsigned* __restrict__ bar)
{
    const int wg  = blockIdx.x;
    const int tid = threadIdx.x;
    const int b   = wg >> 3;          // conv/tail mapping
    const int oct = wg & 7;

    // dense0 mapping: XCD (wg%8) owns ks in [4*xcd, 4*xcd+4), all 16 n-chunks
    const int d_ks = (wg & 7)*4 + ((wg >> 3) & 3);
    const int d_nc = wg >> 5;

    // conv row geometry (pool2 rows per oct: 2,2,2,2,2,2,1,1)
    const int p2lo = (oct < 6) ? 2*oct : 12 + (oct - 6);
    const int p2n  = (oct < 6) ? 2 : 1;
    const int p1n  = 2*p2n + 2;       // pool1 rows incl. halo
    const int p1lo = 2*p2lo;
    const int ilo  = 4*p2lo;          // conv-input row start
    const int inn  = 2*p1n + 2;       // input rows staged

    __shared__ float w1l[864];        // (3,3,6,16)
    __shared__ float w2l[4608];       // (3,3,16,32)
    __shared__ float S45[32];         // per-o sums of w1 action channels
    __shared__ float b1l[16];
    __shared__ float b2l[32];
    __shared__ float bAl[16];
    __shared__ float sS[8];           // current state S_st (persists across steps)
    __shared__ int   prm[12];         // crow,ccol, pr[3], pc[3], valid[3]
    __shared__ float U[4352];         // union: pool1s(3720)+inl | dense0 red | h1l+red2
    unsigned char* inl = (unsigned char*)(U + 3720);   // 896 B

    unsigned* cnt = bar;
    unsigned* gen = bar + 1;

    // ---- one-time weight staging (persists in LDS for all 50 steps) ----
    for (int i = tid; i < 864;  i += 256) w1l[i] = w1[i];
    for (int i = tid; i < 4608; i += 256) w2l[i] = w2[i];
    if (tid < 16){
        b1l[tid] = b1[tid];
        float s4 = 0.f, s5 = 0.f;
        #pragma unroll
        for (int k = 0; k < 9; k++){
            s4 += w1[(k*6 + 4)*16 + tid];
            s5 += w1[(k*6 + 5)*16 + tid];
        }
        S45[tid] = s4; S45[16 + tid] = s5;
    }
    if (tid < 32) b2l[tid] = b2[tid];
    __syncthreads();

    for (int st = 0; st < 50; ++st){
        const float a0 = action[b*100 + st*2 + 0];
        const float a1 = action[b*100 + st*2 + 1];

        // ---- phase A: state update + raster params (WG-local, redundant per oct) ----
        if (st == 0){
            if (tid < 6) sS[tid] = state[b*306 + tid];
        } else {
            if (tid < 6){
                const float* dd = wsDs + b*48 + tid;
                float ds = dd[0]+dd[6]+dd[12]+dd[18]+dd[24]+dd[30]+dd[36]+dd[42];
                sS[tid] += ds;
            }
        }
        __syncthreads();
        if (tid == 0){
            float org0 = origin[2*b], org1 = origin[2*b+1];
            int ccol = (int)(sS[4] / 0.03f + org1);   // trunc == astype(int32)
            int crow = (int)(sS[5] / 0.03f + org0);
            float res0 = res[b*50];
            float lo0 = org0 - (float)crow + 32.0f;
            float lo1 = org1 - (float)ccol + 32.0f;
            prm[0] = crow; prm[1] = ccol;
            #pragma unroll
            for (int p = 0; p < 3; p++){
                int rr = (int)(sS[2*p+1]/res0 + lo0);
                int cc = (int)(sS[2*p  ]/res0 + lo1);
                prm[2+p] = rr; prm[5+p] = cc;
                prm[8+p] = (rr>=0 && rr<64 && cc>=0 && cc<64) ? 1 : 0;
            }
        }
        if (tid < 16) bAl[tid] = b1l[tid] + a0*S45[tid] + a1*S45[16+tid];
        if (oct == 0 && tid < 6) out[b*306 + st*6 + tid] = sS[tid];
        __syncthreads();

        // ---- conv: window gather, conv1+pool1, conv2+pool2 -> wsFlatT[k][b] ----
        {
            const int crow = prm[0], ccol = prm[1];
            for (int idx = tid; idx < inn*64; idx += 256){
                int i = idx >> 6, j = idx & 63;
                int r = crow - 32 + ilo + i;
                int c = ccol - 32 + j;
                float v = (r>=0 && r<256 && c>=0 && c<256) ? env[b*65536 + (r<<8) + c] : 0.f;
                inl[idx] = (unsigned char)v;
            }
            __syncthreads();

            int pr[3], pc[3], pvld[3];
            #pragma unroll
            for (int p = 0; p < 3; p++){ pr[p]=prm[2+p]; pc[p]=prm[5+p]; pvld[p]=prm[8+p]; }

            for (int u = tid; u < p1n*31; u += 256){
                int pl = u / 31;
                int j  = u - pl*31;
                float l[4][4];
                #pragma unroll
                for (int dy = 0; dy < 4; dy++)
                    #pragma unroll
                    for (int dx = 0; dx < 4; dx++)
                        l[dy][dx] = (float)inl[(2*pl + dy)*64 + 2*j + dx];

                float m[16];
                #pragma unroll
                for (int o = 0; o < 16; o++) m[o] = 0.f;   // relu>=0 -> 0 valid for max

                #pragma unroll
                for (int dy = 0; dy < 2; dy++){
                    #pragma unroll
                    for (int dx = 0; dx < 2; dx++){
                        int rg = 2*(p1lo + pl) + dy;
                        int cg = 2*j + dx;
                        bool pf[3]; int pidx[3];
                        #pragma unroll
                        for (int p = 0; p < 3; p++){
                            int kr = pr[p] - rg, kc = pc[p] - cg;
                            pf[p] = pvld[p] && kr >= 0 && kr < 3 && kc >= 0 && kc < 3;
                            pidx[p] = pf[p] ? ((kr*3 + kc)*6 + p)*16 : 0;
                        }
                        #pragma unroll
                        for (int o = 0; o < 16; o++){
                            float v = bAl[o];
                            #pragma unroll
                            for (int kr = 0; kr < 3; kr++)
                                #pragma unroll
                                for (int kc = 0; kc < 3; kc++)
                                    v = fmaf(l[dy+kr][dx+kc], w1l[((kr*3 + kc)*6 + 3)*16 + o], v);
                            if (pf[0]) v += w1l[pidx[0] + o];
                            if (pf[1]) v += w1l[pidx[1] + o];
                            if (pf[2]) v += w1l[pidx[2] + o];
                            v = fmaxf(v, 0.f);
                            m[o] = fmaxf(m[o], v);
                        }
                    }
                }
                float* pd = &U[(pl*31 + j)*20];
                #pragma unroll
                for (int o = 0; o < 16; o++) pd[o] = m[o];
            }
            __syncthreads();

            // conv2+pool2: unit=(pi,jj,oq8), 2x2 quad x 4 out-ch in registers
            const int units = p2n*14*8;
            for (int u = tid; u < units; u += 256){
                int pi  = u / 112;
                int rem = u - pi*112;
                int jj  = rem >> 3;
                int oq  = rem & 7;
                int o0  = oq*4;

                float acc[4][4];
                #pragma unroll
                for (int ps = 0; ps < 4; ps++)
                    #pragma unroll
                    for (int c = 0; c < 4; c++) acc[ps][c] = 0.f;

                #pragma unroll 1
                for (int t9 = 0; t9 < 9; t9++){
                    int kr = t9 / 3, kc = t9 - 3*(t9/3);
                    const float* pb = &U[((2*pi + kr)*31 + (2*jj + kc))*20];
                    const float* wb = &w2l[(kr*3 + kc)*512 + o0];
                    #pragma unroll
                    for (int kib = 0; kib < 4; kib++){
                        float4 q00 = *(const float4*)(pb + kib*4);
                        float4 q01 = *(const float4*)(pb + 20 + kib*4);
                        float4 q10 = *(const float4*)(pb + 620 + kib*4);
                        float4 q11 = *(const float4*)(pb + 640 + kib*4);
                        float pq[4][4] = {
                            {q00.x, q00.y, q00.z, q00.w},
                            {q01.x, q01.y, q01.z, q01.w},
                            {q10.x, q10.y, q10.z, q10.w},
                            {q11.x, q11.y, q11.z, q11.w}};
                        #pragma unroll
                        for (int kk = 0; kk < 4; kk++){
                            float4 wv = *(const float4*)(wb + (kib*4 + kk)*32);
                            #pragma unroll
                            for (int ps = 0; ps < 4; ps++){
                                float pvv = pq[ps][kk];
                                acc[ps][0] = fmaf(pvv, wv.x, acc[ps][0]);
                                acc[ps][1] = fmaf(pvv, wv.y, acc[ps][1]);
                                acc[ps][2] = fmaf(pvv, wv.z, acc[ps][2]);
                                acc[ps][3] = fmaf(pvv, wv.w, acc[ps][3]);
                            }
                        }
                    }
                }
                int gi = p2lo + pi;
                int kb = (gi*14 + jj)*32 + o0;
                #pragma unroll
                for (int c = 0; c < 4; c++){
                    float bb = b2l[o0 + c];
                    float v0 = fmaxf(acc[0][c] + bb, 0.f);
                    float v1 = fmaxf(acc[1][c] + bb, 0.f);
                    float v2 = fmaxf(acc[2][c] + bb, 0.f);
                    float v3 = fmaxf(acc[3][c] + bb, 0.f);
                    wsFlatT[(kb + c)*64 + b] = fmaxf(fmaxf(v0, v1), fmaxf(v2, v3));
                }
            }
        }

        grid_barrier(cnt, gen);

        // ---- dense0: flat-part GEMM, direct-global X (transposed layout) ----
        {
            const int n0 = d_nc*16;
            const int w  = tid >> 6, lane = tid & 63;
            const int mg = lane >> 2, nq = lane & 3;
            const int kbase = d_ks*196 + w*49;
            const float* xp = wsFlatT + kbase*64 + mg*4;
            const float* wp = w0 + (8 + kbase)*256 + n0 + nq*4;

            float acc[4][4];
            #pragma unroll
            for (int i = 0; i < 4; i++)
                #pragma unroll
                for (int c = 0; c < 4; c++) acc[i][c] = 0.f;

            #pragma unroll 7
            for (int k = 0; k < 49; k++){
                float4 x4 = *(const float4*)(xp + k*64);
                float4 w4 = *(const float4*)(wp + k*256);
                acc[0][0]=fmaf(x4.x,w4.x,acc[0][0]); acc[0][1]=fmaf(x4.x,w4.y,acc[0][1]);
                acc[0][2]=fmaf(x4.x,w4.z,acc[0][2]); acc[0][3]=fmaf(x4.x,w4.w,acc[0][3]);
                acc[1][0]=fmaf(x4.y,w4.x,acc[1][0]); acc[1][1]=fmaf(x4.y,w4.y,acc[1][1]);
                acc[1][2]=fmaf(x4.y,w4.z,acc[1][2]); acc[1][3]=fmaf(x4.y,w4.w,acc[1][3]);
                acc[2][0]=fmaf(x4.z,w4.x,acc[2][0]); acc[2][1]=fmaf(x4.z,w4.y,acc[2][1]);
                acc[2][2]=fmaf(x4.z,w4.z,acc[2][2]); acc[2][3]=fmaf(x4.z,w4.w,acc[2][3]);
                acc[3][0]=fmaf(x4.w,w4.x,acc[3][0]); acc[3][1]=fmaf(x4.w,w4.y,acc[3][1]);
                acc[3][2]=fmaf(x4.w,w4.z,acc[3][2]); acc[3][3]=fmaf(x4.w,w4.w,acc[3][3]);
            }

            float* red = U;
            {
                float* rr = red + (w*64 + lane)*17;
                #pragma unroll
                for (int j = 0; j < 16; j++) rr[j] = acc[j>>2][j&3];
            }
            __syncthreads();
            if (tid < 64){
                int mg2 = tid >> 2, nq2 = tid & 3;
                float* dst = wsPart + d_ks*16384 + n0 + nq2*4;
                #pragma unroll
                for (int g = 0; g < 4; g++){
                    float4 v;
                    v.x = red[tid*17+4*g+0] + red[(64+tid)*17+4*g+0] + red[(128+tid)*17+4*g+0] + red[(192+tid)*17+4*g+0];
                    v.y = red[tid*17+4*g+1] + red[(64+tid)*17+4*g+1] + red[(128+tid)*17+4*g+1] + red[(192+tid)*17+4*g+1];
                    v.z = red[tid*17+4*g+2] + red[(64+tid)*17+4*g+2] + red[(128+tid)*17+4*g+2] + red[(192+tid)*17+4*g+2];
                    v.w = red[tid*17+4*g+3] + red[(64+tid)*17+4*g+3] + red[(128+tid)*17+4*g+3] + red[(192+tid)*17+4*g+3];
                    int bb = mg2*4 + g;
                    *(float4*)(dst + bb*256) = v;
                }
            }
        }

        grid_barrier(cnt, gen);

        // ---- tail: h1 reduce + dense1 (32 cols per oct) + dense2 partials ----
        {
            float hacc = b0[tid];
            const float* pp = wsPart + b*256 + tid;
            #pragma unroll
            for (int ks2 = 0; ks2 < 32; ks2++) hacc += pp[ks2*16384];
            #pragma unroll
            for (int j = 0; j < 6; j++) hacc = fmaf(sS[j], w0[j*256 + tid], hacc);
            hacc = fmaf(a0, w0[1536 + tid], hacc);
            hacc = fmaf(a1, w0[1792 + tid], hacc);
            U[tid] = fmaxf(hacc, 0.f);            // h1l
            __syncthreads();

            int colL = tid >> 3, kg = tid & 7;
            int col  = oct*32 + colL;
            float d1 = 0.f;
            const float* wc = w1d + kg*32*256 + col;
            #pragma unroll 8
            for (int kk = 0; kk < 32; kk++)
                d1 = fmaf(U[kg*32 + kk], wc[kk*256], d1);
            U[256 + colL*8 + kg] = d1;
            __syncthreads();

            if (tid < 32){
                float h2 = b1d[oct*32 + tid];
                const float* rr = U + 256 + tid*8;
                #pragma unroll
                for (int g = 0; g < 8; g++) h2 += rr[g];
                h2 = fmaxf(h2, 0.f);
                float p[6];
                const float* wr = w2d + (oct*32 + tid)*6;
                #pragma unroll
                for (int j = 0; j < 6; j++) p[j] = h2 * wr[j];
                #pragma unroll
                for (int off = 16; off > 0; off >>= 1){
                    #pragma unroll
                    for (int j = 0; j < 6; j++) p[j] += __shfl_down(p[j], off, 64);
                }
                if (tid == 0){
                    float* dd = wsDs + b*48 + oct*6;
                    #pragma unroll
                    for (int j = 0; j < 6; j++) dd[j] = p[j] + (oct == 0 ? b2d[j] : 0.f);
                }
            }
        }

        grid_barrier(cnt, gen);
    }

    // ---- epilogue: final state S_50 ----
    if (oct == 0 && tid < 6){
        const float* dd = wsDs + b*48 + tid;
        float ds = dd[0]+dd[6]+dd[12]+dd[18]+dd[24]+dd[30]+dd[36]+dd[42];
        out[b*306 + 300 + tid] = sS[tid] + ds;
    }
}

// ---------------- launch ----------------
extern "C" void kernel_launch(void* const* d_in, const int* in_sizes, int n_in,
                              void* d_out, int out_size, void* d_ws, size_t ws_size,
                              hipStream_t stream)
{
    (void)in_sizes; (void)n_in; (void)out_size; (void)ws_size;
    const float* action = (const float*)d_in[0];
    const float* state  = (const float*)d_in[1];
    const float* res    = (const float*)d_in[2];
    const float* env    = (const float*)d_in[3];
    const float* origin = (const float*)d_in[4];
    const float* w1  = (const float*)d_in[5];
    const float* b1  = (const float*)d_in[6];
    const float* w2  = (const float*)d_in[7];
    const float* b2  = (const float*)d_in[8];
    const float* w0  = (const float*)d_in[9];
    const float* b0  = (const float*)d_in[10];
    const float* w1d = (const float*)d_in[11];
    const float* b1d = (const float*)d_in[12];
    const float* w2d = (const float*)d_in[13];
    const float* b2d = (const float*)d_in[14];
    float* out = (float*)d_out;

    // ws layout (floats): bar[16] | flatT[401408] | part[524288] | ds[3072]
    float* wsF     = (float*)d_ws;
    unsigned* bar  = (unsigned*)d_ws;
    float* wsFlatT = wsF + 16;
    float* wsPart  = wsF + 16 + 401408;
    float* wsDs    = wsF + 16 + 401408 + 524288;

    hipMemsetAsync(d_ws, 0, 64, stream);   // barrier counters must start at 0
    k_persist<<<dim3(NWG), dim3(256), 0, stream>>>(
        action, state, res, env, origin, w1, b1, w2, b2, w0, b0,
        w1d, b1d, w2d, b2d, out, wsFlatT, wsPart, wsDs, bar);
}

// Round 4
// 2266.857 us; speedup vs baseline: 4.8770x; 4.8770x over previous
//
#include <hip/hip_runtime.h>

// B=64, T=50, ROWS=COLS=64, RES=0.03, H_FULL=W_FULL=256
// flat = 14*14*32 = 6272 (wsFlat[b][k] contiguous per batch)
// out: (64,51,6) float32
//
// Structure: 101 graph nodes:
//   F0 D0 F1 D1 ... F49 D49 F50
// k_front(st): [tail of step st-1: h1 = b0+parts+state/action rows; dense1; dense2;
//               s_st = s_{st-1}+ds] + [params(s_st) + conv stack -> wsFlat]
// k_dense0(st): flat-part of dense0 -> wsPart[32][64][256]
// State double-buffered by step parity: read wsS[(st-1)&1], write wsS[st&1].

// ---------------- k_front: tail(st-1) + conv(st) ----------------
// Grid: 128 WGs x 512 thr; WG = (b = wg>>1, half h = wg&1). half owns 7 pool2 rows.
__global__ __launch_bounds__(512, 2)
void k_front(const float* __restrict__ action, const float* __restrict__ state,
             const float* __restrict__ res, const float* __restrict__ env,
             const float* __restrict__ origin,
             const float* __restrict__ w1, const float* __restrict__ b1,
             const float* __restrict__ w2, const float* __restrict__ b2,
             const float* __restrict__ w0, const float* __restrict__ b0,
             const float* __restrict__ w1d, const float* __restrict__ b1d,
             const float* __restrict__ w2d, const float* __restrict__ b2d,
             const float* __restrict__ wsPart, float* __restrict__ wsS,
             float* __restrict__ wsFlat, float* __restrict__ out, int st)
{
    const int wg  = blockIdx.x;
    const int b   = wg >> 1;
    const int h   = wg & 1;
    const int tid = threadIdx.x;

    __shared__ float w1l[864];           // (3,3,6,16)
    __shared__ float w2l[4608];          // (3,3,16,32)
    __shared__ float S45[32];
    __shared__ float b1l[16];
    __shared__ float b2l[32];
    __shared__ float bAl[16];
    __shared__ float sSl[8];
    __shared__ int   prm[12];
    __shared__ float h1l[256];
    __shared__ float pbuf[512];
    __shared__ float wred[24];
    __shared__ float pool1s[16*31*20];   // 39680 B
    __shared__ unsigned char inl[34*64]; // 2176 B

    // ---- weight staging (every launch; L2/L3-resident) ----
    for (int i = tid; i < 864;  i += 512) w1l[i] = w1[i];
    for (int i = tid; i < 4608; i += 512) w2l[i] = w2[i];
    if (tid < 16){
        b1l[tid] = b1[tid];
        float s4 = 0.f, s5 = 0.f;
        #pragma unroll
        for (int k = 0; k < 9; k++){
            s4 += w1[(k*6 + 4)*16 + tid];
            s5 += w1[(k*6 + 5)*16 + tid];
        }
        S45[tid] = s4; S45[16 + tid] = s5;
    }
    if (tid < 32) b2l[tid] = b2[tid];

    // ---- tail phase: compute s_st ----
    if (st == 0){
        if (tid < 6) sSl[tid] = state[b*306 + tid];
        __syncthreads();
    } else {
        const float* sp = wsS + ((st-1)&1)*512 + b*8;
        const float a0p = action[b*100 + (st-1)*2 + 0];
        const float a1p = action[b*100 + (st-1)*2 + 1];
        const int col = tid & 255, kh = tid >> 8;

        // h1 partials: kh=0 adds bias+state/action rows + parts 0..15; kh=1 parts 16..31
        float hacc;
        if (kh == 0){
            hacc = b0[col];
            #pragma unroll
            for (int j = 0; j < 6; j++) hacc = fmaf(sp[j], w0[j*256 + col], hacc);
            hacc = fmaf(a0p, w0[1536 + col], hacc);
            hacc = fmaf(a1p, w0[1792 + col], hacc);
        } else hacc = 0.f;
        const float* pp = wsPart + kh*16*16384 + b*256 + col;
        #pragma unroll
        for (int ks = 0; ks < 16; ks++) hacc += pp[ks*16384];
        pbuf[tid] = hacc;
        __syncthreads();
        if (tid < 256) h1l[tid] = fmaxf(pbuf[tid] + pbuf[256 + tid], 0.f);
        __syncthreads();

        // dense1: 512 threads = 256 cols x 2 K-halves
        {
            const int k0 = (tid >> 8)*128;
            float d0 = 0.f, d1 = 0.f;
            const float* wc = w1d + k0*256 + col;
            #pragma unroll 4
            for (int k = 0; k < 128; k += 2){
                d0 = fmaf(h1l[k0 + k],     wc[k*256],       d0);
                d1 = fmaf(h1l[k0 + k + 1], wc[(k+1)*256],   d1);
            }
            pbuf[tid] = d0 + d1;
        }
        __syncthreads();

        // dense2 + ds
        if (tid < 256){
            float h2 = fmaxf(pbuf[tid] + pbuf[256 + tid] + b1d[tid], 0.f);
            float p[6];
            const float* wr = w2d + tid*6;
            #pragma unroll
            for (int j = 0; j < 6; j++) p[j] = h2 * wr[j];
            #pragma unroll
            for (int off = 32; off > 0; off >>= 1){
                #pragma unroll
                for (int j = 0; j < 6; j++) p[j] += __shfl_down(p[j], off, 64);
            }
            if ((tid & 63) == 0){
                #pragma unroll
                for (int j = 0; j < 6; j++) wred[(tid >> 6)*6 + j] = p[j];
            }
        }
        __syncthreads();
        if (tid < 6){
            float ds = wred[tid] + wred[6+tid] + wred[12+tid] + wred[18+tid] + b2d[tid];
            sSl[tid] = sp[tid] + ds;
        }
        __syncthreads();
    }

    if (h == 0 && tid < 6){
        out[b*306 + st*6 + tid] = sSl[tid];
        wsS[(st & 1)*512 + b*8 + tid] = sSl[tid];
    }
    if (st >= 50) return;

    // ---- params + conv constants ----
    if (tid == 0){
        float org0 = origin[2*b], org1 = origin[2*b+1];
        int ccol = (int)(sSl[4] / 0.03f + org1);   // trunc == astype(int32)
        int crow = (int)(sSl[5] / 0.03f + org0);
        float res0 = res[b*50];
        float lo0 = org0 - (float)crow + 32.0f;
        float lo1 = org1 - (float)ccol + 32.0f;
        prm[0] = crow; prm[1] = ccol;
        #pragma unroll
        for (int p = 0; p < 3; p++){
            int rr = (int)(sSl[2*p+1]/res0 + lo0);
            int cc = (int)(sSl[2*p  ]/res0 + lo1);
            prm[2+p] = rr; prm[5+p] = cc;
            prm[8+p] = (rr>=0 && rr<64 && cc>=0 && cc<64) ? 1 : 0;
        }
    }
    {
        const float a0 = action[b*100 + st*2 + 0];
        const float a1 = action[b*100 + st*2 + 1];
        if (tid < 16) bAl[tid] = b1l[tid] + a0*S45[tid] + a1*S45[16+tid];
    }
    __syncthreads();

    // ---- conv geometry for this half ----
    const int p2lo = h*7;            // pool2 rows [p2lo, p2lo+7)
    const int p1lo = 14*h;           // pool1 rows [p1lo, p1lo+16) incl. halo
    const int ilo  = 28*h;           // input rows [ilo, ilo+34)

    // window gather
    {
        const int crow = prm[0], ccol = prm[1];
        for (int idx = tid; idx < 34*64; idx += 512){
            int i = idx >> 6, j = idx & 63;
            int r = crow - 32 + ilo + i;
            int c = ccol - 32 + j;
            float v = (r>=0 && r<256 && c>=0 && c<256) ? env[b*65536 + (r<<8) + c] : 0.f;
            inl[idx] = (unsigned char)v;
        }
    }
    __syncthreads();

    // conv1 + pool1 (16 pool1 rows x 31 cols = 496 units)
    {
        int pr[3], pc[3], pvld[3];
        #pragma unroll
        for (int p = 0; p < 3; p++){ pr[p]=prm[2+p]; pc[p]=prm[5+p]; pvld[p]=prm[8+p]; }

        for (int u = tid; u < 496; u += 512){
            int pl = u / 31;
            int j  = u - pl*31;
            float l[4][4];
            #pragma unroll
            for (int dy = 0; dy < 4; dy++)
                #pragma unroll
                for (int dx = 0; dx < 4; dx++)
                    l[dy][dx] = (float)inl[(2*pl + dy)*64 + 2*j + dx];

            float m[16];
            #pragma unroll
            for (int o = 0; o < 16; o++) m[o] = 0.f;   // relu>=0

            #pragma unroll
            for (int dy = 0; dy < 2; dy++){
                #pragma unroll
                for (int dx = 0; dx < 2; dx++){
                    int rg = 2*(p1lo + pl) + dy;
                    int cg = 2*j + dx;
                    bool pf[3]; int pidx[3];
                    #pragma unroll
                    for (int p = 0; p < 3; p++){
                        int kr = pr[p] - rg, kc = pc[p] - cg;
                        pf[p] = pvld[p] && kr >= 0 && kr < 3 && kc >= 0 && kc < 3;
                        pidx[p] = pf[p] ? ((kr*3 + kc)*6 + p)*16 : 0;
                    }
                    #pragma unroll
                    for (int o = 0; o < 16; o++){
                        float v = bAl[o];
                        #pragma unroll
                        for (int kr = 0; kr < 3; kr++)
                            #pragma unroll
                            for (int kc = 0; kc < 3; kc++)
                                v = fmaf(l[dy+kr][dx+kc], w1l[((kr*3 + kc)*6 + 3)*16 + o], v);
                        if (pf[0]) v += w1l[pidx[0] + o];
                        if (pf[1]) v += w1l[pidx[1] + o];
                        if (pf[2]) v += w1l[pidx[2] + o];
                        v = fmaxf(v, 0.f);
                        m[o] = fmaxf(m[o], v);
                    }
                }
            }
            float* pd = &pool1s[(pl*31 + j)*20];
            #pragma unroll
            for (int o = 0; o < 16; o++) pd[o] = m[o];
        }
    }
    __syncthreads();

    // conv2 + pool2 -> wsFlat (7 pool2 rows x 14 cols x 8 ch-quads = 784 units)
    for (int u = tid; u < 784; u += 512){
        int pi  = u / 112;
        int rem = u - pi*112;
        int jj  = rem >> 3;
        int oq  = rem & 7;
        int o0  = oq*4;

        float acc[4][4];
        #pragma unroll
        for (int ps = 0; ps < 4; ps++)
            #pragma unroll
            for (int c = 0; c < 4; c++) acc[ps][c] = 0.f;

        #pragma unroll 1
        for (int t9 = 0; t9 < 9; t9++){
            int kr = t9 / 3, kc = t9 - 3*(t9/3);
            const float* pb = &pool1s[((2*pi + kr)*31 + (2*jj + kc))*20];
            const float* wb = &w2l[(kr*3 + kc)*512 + o0];
            #pragma unroll
            for (int kib = 0; kib < 4; kib++){
                float4 q00 = *(const float4*)(pb + kib*4);
                float4 q01 = *(const float4*)(pb + 20 + kib*4);
                float4 q10 = *(const float4*)(pb + 620 + kib*4);
                float4 q11 = *(const float4*)(pb + 640 + kib*4);
                float pq[4][4] = {
                    {q00.x, q00.y, q00.z, q00.w},
                    {q01.x, q01.y, q01.z, q01.w},
                    {q10.x, q10.y, q10.z, q10.w},
                    {q11.x, q11.y, q11.z, q11.w}};
                #pragma unroll
                for (int kk = 0; kk < 4; kk++){
                    float4 wv = *(const float4*)(wb + (kib*4 + kk)*32);
                    #pragma unroll
                    for (int ps = 0; ps < 4; ps++){
                        float pvv = pq[ps][kk];
                        acc[ps][0] = fmaf(pvv, wv.x, acc[ps][0]);
                        acc[ps][1] = fmaf(pvv, wv.y, acc[ps][1]);
                        acc[ps][2] = fmaf(pvv, wv.z, acc[ps][2]);
                        acc[ps][3] = fmaf(pvv, wv.w, acc[ps][3]);
                    }
                }
            }
        }
        int gi = p2lo + pi;
        float* dst = wsFlat + b*6272 + (gi*14 + jj)*32 + o0;
        #pragma unroll
        for (int c = 0; c < 4; c++){
            float bb = b2l[o0 + c];
            float v0 = fmaxf(acc[0][c] + bb, 0.f);
            float v1 = fmaxf(acc[1][c] + bb, 0.f);
            float v2 = fmaxf(acc[2][c] + bb, 0.f);
            float v3 = fmaxf(acc[3][c] + bb, 0.f);
            dst[c] = fmaxf(fmaxf(v0, v1), fmaxf(v2, v3));
        }
    }
}

// ---------------- k_dense0: flat-part K-split GEMM ----------------
// Grid: 512 WGs = ks(32) x nc(16), XCD-swizzled. WG = 4 waves.
// LDS X staged k-major: xs[k][68] (k in [0,196) local), GEMM reads one b128/k.
__global__ __launch_bounds__(256, 2)
void k_dense0(const float* __restrict__ w0, const float* __restrict__ wsFlat,
              float* __restrict__ wsPart)
{
    const int blk = blockIdx.x;
    const int lid = (blk & 7)*64 + (blk >> 3);  // XCD-swizzle
    const int ks = lid >> 4;       // 0..31
    const int nc = lid & 15;       // 0..15
    const int n0 = nc*16;
    const int tid  = threadIdx.x;
    const int w    = tid >> 6;
    const int lane = tid & 63;
    const int mg = lane >> 2;
    const int nq = lane & 3;
    const int kbase = ks*196;

    __shared__ float xs[196*68];   // 53312 B; reused as reduce buf

    // stage X k-major: xs[k][b] = wsFlat[b][kbase+k]
    for (int idx = tid; idx < 3136; idx += 256){
        int b = idx / 49;
        int r = idx - b*49;
        float4 v = *(const float4*)(wsFlat + b*6272 + kbase + 4*r);
        xs[(4*r + 0)*68 + b] = v.x;
        xs[(4*r + 1)*68 + b] = v.y;
        xs[(4*r + 2)*68 + b] = v.z;
        xs[(4*r + 3)*68 + b] = v.w;
    }
    __syncthreads();

    float acc[4][4];
    #pragma unroll
    for (int i = 0; i < 4; i++)
        #pragma unroll
        for (int c = 0; c < 4; c++) acc[i][c] = 0.f;

    const float* xk = xs + (49*w)*68 + mg*4;
    const float* wp = w0 + (8 + kbase + 49*w)*256 + n0 + nq*4;
    #pragma unroll 7
    for (int k = 0; k < 49; k++){
        float4 x4 = *(const float4*)(xk + k*68);
        float4 w4 = *(const float4*)(wp + k*256);
        acc[0][0]=fmaf(x4.x,w4.x,acc[0][0]); acc[0][1]=fmaf(x4.x,w4.y,acc[0][1]);
        acc[0][2]=fmaf(x4.x,w4.z,acc[0][2]); acc[0][3]=fmaf(x4.x,w4.w,acc[0][3]);
        acc[1][0]=fmaf(x4.y,w4.x,acc[1][0]); acc[1][1]=fmaf(x4.y,w4.y,acc[1][1]);
        acc[1][2]=fmaf(x4.y,w4.z,acc[1][2]); acc[1][3]=fmaf(x4.y,w4.w,acc[1][3]);
        acc[2][0]=fmaf(x4.z,w4.x,acc[2][0]); acc[2][1]=fmaf(x4.z,w4.y,acc[2][1]);
        acc[2][2]=fmaf(x4.z,w4.z,acc[2][2]); acc[2][3]=fmaf(x4.z,w4.w,acc[2][3]);
        acc[3][0]=fmaf(x4.w,w4.x,acc[3][0]); acc[3][1]=fmaf(x4.w,w4.y,acc[3][1]);
        acc[3][2]=fmaf(x4.w,w4.z,acc[3][2]); acc[3][3]=fmaf(x4.w,w4.w,acc[3][3]);
    }
    __syncthreads();   // all waves done reading xs

    // cross-wave reduce: red[(w*64+lane)][16] stride 17
    float* red = xs;
    {
        float* rr = red + (w*64 + lane)*17;
        #pragma unroll
        for (int j = 0; j < 16; j++) rr[j] = acc[j>>2][j&3];
    }
    __syncthreads();
    if (tid < 64){
        int mg2 = tid >> 2, nq2 = tid & 3;
        float* dst = wsPart + ks*16384 + n0 + nq2*4;
        #pragma unroll
        for (int g = 0; g < 4; g++){
            float4 v;
            v.x = red[tid*17+4*g+0] + red[(64+tid)*17+4*g+0] + red[(128+tid)*17+4*g+0] + red[(192+tid)*17+4*g+0];
            v.y = red[tid*17+4*g+1] + red[(64+tid)*17+4*g+1] + red[(128+tid)*17+4*g+1] + red[(192+tid)*17+4*g+1];
            v.z = red[tid*17+4*g+2] + red[(64+tid)*17+4*g+2] + red[(128+tid)*17+4*g+2] + red[(192+tid)*17+4*g+2];
            v.w = red[tid*17+4*g+3] + red[(64+tid)*17+4*g+3] + red[(128+tid)*17+4*g+3] + red[(192+tid)*17+4*g+3];
            int bb = mg2*4 + g;
            *(float4*)(dst + bb*256) = v;
        }
    }
}

// ---------------- launch ----------------
extern "C" void kernel_launch(void* const* d_in, const int* in_sizes, int n_in,
                              void* d_out, int out_size, void* d_ws, size_t ws_size,
                              hipStream_t stream)
{
    (void)in_sizes; (void)n_in; (void)out_size; (void)ws_size;
    const float* action = (const float*)d_in[0];
    const float* state  = (const float*)d_in[1];
    const float* res    = (const float*)d_in[2];
    const float* env    = (const float*)d_in[3];
    const float* origin = (const float*)d_in[4];
    const float* w1  = (const float*)d_in[5];
    const float* b1  = (const float*)d_in[6];
    const float* w2  = (const float*)d_in[7];
    const float* b2  = (const float*)d_in[8];
    const float* w0  = (const float*)d_in[9];
    const float* b0  = (const float*)d_in[10];
    const float* w1d = (const float*)d_in[11];
    const float* b1d = (const float*)d_in[12];
    const float* w2d = (const float*)d_in[13];
    const float* b2d = (const float*)d_in[14];
    float* out = (float*)d_out;

    // ws layout (floats): wsS[2][512] | flat[401408] | part[524288]
    float* wsF    = (float*)d_ws;
    float* wsS    = wsF;
    float* wsFlat = wsF + 1024;
    float* wsPart = wsF + 1024 + 401408;

    for (int st = 0; st <= 50; ++st){
        k_front<<<dim3(128), dim3(512), 0, stream>>>(
            action, state, res, env, origin, w1, b1, w2, b2, w0, b0,
            w1d, b1d, w2d, b2d, wsPart, wsS, wsFlat, out, st);
        if (st < 50)
            k_dense0<<<dim3(512), dim3(256), 0, stream>>>(w0, wsFlat, wsPart);
    }
}